// Round 5
// baseline (92.010 us; speedup 1.0000x reference)
//
#include <hip/hip_runtime.h>
#include <hip/hip_bf16.h>

// Problem dims (fixed)
#define BB   8
#define LL   32
#define NINV 64
#define NOUTV 16
#define DINV 128
#define EE   64
#define DCV  512

#define EPSF 1e-8f
#define LBDF 1e-3f
// 32 * ln(2*pi)
#define SUM_LN2PI 58.8120661250990508f

// ---------------------------------------------------------------------------
// Kernel 1: c[b,l,e] = ctx[b,l,:]@Wc + bc   (blocks 0..255)
//           actn[b,n] = sigmoid(inu[b,n,:]@Wa + ba)  (blocks 256..263)
// ---------------------------------------------------------------------------
__global__ __launch_bounds__(64) void prep_kernel(
    const float* __restrict__ ctx, const float* __restrict__ Wc, const float* __restrict__ bc,
    const float* __restrict__ inu, const float* __restrict__ Wa, const float* __restrict__ ba,
    float* __restrict__ c_out, float* __restrict__ actn_out)
{
    const int blk = blockIdx.x;
    const int t = threadIdx.x;
    __shared__ float row[DCV];
    if (blk < BB * LL) {
        const float* cr = ctx + (size_t)blk * DCV;
        #pragma unroll
        for (int i = 0; i < DCV / 64; ++i) row[t + 64 * i] = cr[t + 64 * i];
        __syncthreads();
        float acc = bc[t];
        for (int d = 0; d < DCV; ++d) acc = fmaf(row[d], Wc[d * EE + t], acc);
        c_out[blk * EE + t] = acc;
    } else {
        const int b = blk - BB * LL;
        const float* ir = inu + ((size_t)b * NINV + t) * DINV;
        float acc = ba[0];
        for (int d = 0; d < DINV; ++d) acc = fmaf(ir[d], Wa[d], acc);
        actn_out[b * NINV + t] = 1.0f / (1.0f + expf(-acc));
    }
}

// ---------------------------------------------------------------------------
// Kernel 2: block (n,o):
//   priors[b,e] = sum_d inu[b,n,d] * rw[n,o,d,e]   (8x128 @ 128x64)
//   u[b,n,o,e]  = priors[b,:] @ Wu + bu
// ---------------------------------------------------------------------------
__global__ __launch_bounds__(256) void priors_u_kernel(
    const float* __restrict__ inu, const float* __restrict__ rw,
    const float* __restrict__ Wu, const float* __restrict__ bu,
    float* __restrict__ u_out)
{
    const int no = blockIdx.x;      // n*16+o
    const int n  = no >> 4;
    const int oo = no & 15;
    const int tid = threadIdx.x;

    __shared__ float inu_sh[BB * DINV];   // 4 KB
    __shared__ float pri_sh[BB * EE];     // 2 KB

    {   // stage inu[:, n, :]
        const int b = tid >> 5;
        const int i = (tid & 31) * 4;
        const float4 s = *(const float4*)(inu + ((size_t)b * NINV + n) * DINV + i);
        *(float4*)(inu_sh + b * DINV + i) = s;
    }
    __syncthreads();

    const int bg = tid >> 6;   // 0..3 -> handles b = 2bg, 2bg+1
    const int e  = tid & 63;
    const float* rwp = rw + (size_t)no * DINV * EE + e;
    const float* r0 = inu_sh + (bg * 2) * DINV;
    const float* r1 = inu_sh + (bg * 2 + 1) * DINV;
    float a0 = 0.0f, a1 = 0.0f;
    for (int d = 0; d < DINV; ++d) {
        const float w = rwp[d * EE];
        a0 = fmaf(r0[d], w, a0);
        a1 = fmaf(r1[d], w, a1);
    }
    pri_sh[(bg * 2) * EE + e] = a0;
    pri_sh[(bg * 2 + 1) * EE + e] = a1;
    __syncthreads();

    float b0 = bu[e], b1 = b0;
    const float* p0 = pri_sh + (bg * 2) * EE;
    const float* p1 = pri_sh + (bg * 2 + 1) * EE;
    for (int e1 = 0; e1 < EE; ++e1) {
        const float w = Wu[e1 * EE + e];
        b0 = fmaf(p0[e1], w, b0);
        b1 = fmaf(p1[e1], w, b1);
    }
    u_out[(((size_t)(bg * 2) * NINV + n) * NOUTV + oo) * EE + e] = b0;
    u_out[(((size_t)(bg * 2 + 1) * NINV + n) * NOUTV + oo) * EE + e] = b1;
}

// ---------------------------------------------------------------------------
// Kernel 3: one 512-thread workgroup per (b,l).
// 512 threads = 8 waves = 2 waves/SIMD at 1 block/CU -> 256-VGPR budget.
// Thread owns TWO (n,o) pairs sharing o: n0=(w<<2)|(l>>4), n1=n0+32.
// Round-5 change: Wv staged in LDS. The wave-uniform Wv row address was
// scalarized to s_load (256 B/row into 64 SGPRs) -> only 1 row in flight
// (SGPR file ~102) -> serial SMEM latency chain = the 57% idle in round 4.
// LDS broadcast ds_read_b128 pipelines via fine-grained lgkmcnt instead.
// ---------------------------------------------------------------------------
__global__ __launch_bounds__(512, 2) void votes_em_kernel(
    const float* __restrict__ u_all, const float* __restrict__ c_all,
    const float* __restrict__ actn_all, const unsigned char* __restrict__ mask_all,
    const float* __restrict__ Wv, const float* __restrict__ bv,
    const float* __restrict__ beta_u, const float* __restrict__ beta_a,
    float* __restrict__ out_mu, float* __restrict__ out_r)
{
    const int bl = blockIdx.x;           // 0..255
    const int b = bl >> 5;
    const int tid = threadIdx.x;
    const int lane = tid & 63;
    const int wid = tid >> 6;            // wave id 0..7
    const int o = lane & 15;
    const int n0 = (wid << 2) | (lane >> 4);   // 0..31
    const int n1 = n0 + 32;                    // 32..63
    const int e_f = lane;                      // finalize role: e = lane,
    const int o_f0 = wid;                      // o in {wid, wid+8}
    const int o_f1 = wid + 8;

    __shared__ float wv_sh[EE * EE];             // 16 KB
    __shared__ float c_sh[EE];
    __shared__ float actn_sh[NINV];
    __shared__ float red[8][NOUTV][EE + 4];      // 34.8 KB
    __shared__ float red_s[8][NOUTV];
    __shared__ float mu_sh[NOUTV][EE + 4];
    __shared__ float inv2s_sh[NOUTV][EE + 4];
    __shared__ float sumhl_sh[NOUTV];
    __shared__ float logact_sh[NOUTV];

    {   // stage Wv (4096 floats = 1024 float4, 512 threads x 2)
        const float4* src = (const float4*)Wv;
        float4* dst = (float4*)wv_sh;
        dst[tid] = src[tid];
        dst[tid + 512] = src[tid + 512];
    }
    if (tid < EE) c_sh[tid] = c_all[bl * EE + tid];
    else if (tid >= 64 && tid < 128) actn_sh[tid - 64] = actn_all[b * NINV + (tid - 64)];
    __syncthreads();

    // ---- votes[n,o,e] = sum_e1 tanh(u[e1]+c[e1]) * Wv[e1][e] + bv[e] ----
    float v0[EE], v1[EE];
    #pragma unroll
    for (int e = 0; e < EE; ++e) { v0[e] = bv[e]; v1[e] = v0[e]; }
    const float4* u4_0 = (const float4*)(u_all + (((size_t)b * NINV + n0) * NOUTV + o) * EE);
    const float4* u4_1 = (const float4*)(u_all + (((size_t)b * NINV + n1) * NOUTV + o) * EE);
    float4 uu0 = u4_0[0];
    float4 uu1 = u4_1[0];
    for (int cc = 0; cc < 16; ++cc) {
        const float4 nx0 = (cc < 15) ? u4_0[cc + 1] : uu0;
        const float4 nx1 = (cc < 15) ? u4_1[cc + 1] : uu1;
        #pragma unroll
        for (int j = 0; j < 4; ++j) {
            const int e1 = cc * 4 + j;
            const float ce = c_sh[e1];
            const float x0 = ((const float*)&uu0)[j] + ce;
            const float x1 = ((const float*)&uu1)[j] + ce;
            // tanh(x) = 1 - 2/(e^{2x}+1)
            const float t0 = 1.0f - 2.0f / (__expf(2.0f * x0) + 1.0f);
            const float t1 = 1.0f - 2.0f / (__expf(2.0f * x1) + 1.0f);
            const float4* wr = (const float4*)&wv_sh[e1 * EE];  // uniform -> LDS broadcast
            #pragma unroll
            for (int e4 = 0; e4 < EE / 4; ++e4) {
                const float4 w = wr[e4];
                v0[e4 * 4 + 0] = fmaf(t0, w.x, v0[e4 * 4 + 0]);
                v1[e4 * 4 + 0] = fmaf(t1, w.x, v1[e4 * 4 + 0]);
                v0[e4 * 4 + 1] = fmaf(t0, w.y, v0[e4 * 4 + 1]);
                v1[e4 * 4 + 1] = fmaf(t1, w.y, v1[e4 * 4 + 1]);
                v0[e4 * 4 + 2] = fmaf(t0, w.z, v0[e4 * 4 + 2]);
                v1[e4 * 4 + 2] = fmaf(t1, w.z, v1[e4 * 4 + 2]);
                v0[e4 * 4 + 3] = fmaf(t0, w.w, v0[e4 * 4 + 3]);
                v1[e4 * 4 + 3] = fmaf(t1, w.w, v1[e4 * 4 + 3]);
            }
        }
        uu0 = nx0;
        uu1 = nx1;
    }

    const unsigned char msk0 = mask_all[b * NINV + n0];
    const unsigned char msk1 = mask_all[b * NINV + n1];
    float r_loc0 = 1.0f / 16.0f;
    float r_loc1 = 1.0f / 16.0f;

    for (int it = 0; it < 3; ++it) {
        // ---- ar / r1 ----
        float ar0 = actn_sh[n0] * r_loc0;
        float ar1 = actn_sh[n1] * r_loc1;
        // normalize over o (lane&15 groups), per pair
        float s0 = ar0, s1 = ar1;
        s0 += __shfl_xor(s0, 1, 64);  s1 += __shfl_xor(s1, 1, 64);
        s0 += __shfl_xor(s0, 2, 64);  s1 += __shfl_xor(s1, 2, 64);
        s0 += __shfl_xor(s0, 4, 64);  s1 += __shfl_xor(s1, 4, 64);
        s0 += __shfl_xor(s0, 8, 64);  s1 += __shfl_xor(s1, 8, 64);
        ar0 = ar0 / (s0 + EPSF);
        ar1 = ar1 / (s1 + EPSF);
        // per-o partial sum over this wave's 8 n's (pairs share o)
        float p = ar0 + ar1;
        p += __shfl_xor(p, 16, 64);
        p += __shfl_xor(p, 32, 64);
        if (lane < NOUTV) red_s[wid][lane] = p;
        __syncthreads();                                  // (1)
        float arsum = 0.0f;
        #pragma unroll
        for (int w2 = 0; w2 < 8; ++w2) arsum += red_s[w2][o];
        const float inv_ars = 1.0f / (arsum + EPSF);
        const float r1_0 = ar0 * inv_ars;
        const float r1_1 = ar1 * inv_ars;

        // ---- mu: sum_n r1*v ----
        #pragma unroll
        for (int e4 = 0; e4 < EE / 4; ++e4) {
            float t0 = fmaf(r1_0, v0[e4 * 4 + 0], r1_1 * v1[e4 * 4 + 0]);
            float t1 = fmaf(r1_0, v0[e4 * 4 + 1], r1_1 * v1[e4 * 4 + 1]);
            float t2 = fmaf(r1_0, v0[e4 * 4 + 2], r1_1 * v1[e4 * 4 + 2]);
            float t3 = fmaf(r1_0, v0[e4 * 4 + 3], r1_1 * v1[e4 * 4 + 3]);
            t0 += __shfl_xor(t0, 16, 64); t0 += __shfl_xor(t0, 32, 64);
            t1 += __shfl_xor(t1, 16, 64); t1 += __shfl_xor(t1, 32, 64);
            t2 += __shfl_xor(t2, 16, 64); t2 += __shfl_xor(t2, 32, 64);
            t3 += __shfl_xor(t3, 16, 64); t3 += __shfl_xor(t3, 32, 64);
            if (lane < NOUTV)
                *(float4*)&red[wid][lane][e4 * 4] = make_float4(t0, t1, t2, t3);
        }
        __syncthreads();                                  // (2)
        float mu_f0 = 0.0f, mu_f1 = 0.0f;
        #pragma unroll
        for (int w2 = 0; w2 < 8; ++w2) {
            mu_f0 += red[w2][o_f0][e_f];
            mu_f1 += red[w2][o_f1][e_f];
        }

        if (it == 2) {
            out_mu[bl * 1024 + o_f0 * EE + e_f] = mu_f0;
            out_mu[bl * 1024 + o_f1 * EE + e_f] = mu_f1;
            break;
        }
        mu_sh[o_f0][e_f] = mu_f0;
        mu_sh[o_f1][e_f] = mu_f1;
        __syncthreads();                                  // (3)

        // ---- sigma: sum_n r1*(v-mu)^2 ----
        #pragma unroll
        for (int e4 = 0; e4 < EE / 4; ++e4) {
            const float4 m4 = *(const float4*)&mu_sh[o][e4 * 4];
            float d00 = v0[e4 * 4 + 0] - m4.x, d10 = v1[e4 * 4 + 0] - m4.x;
            float d01 = v0[e4 * 4 + 1] - m4.y, d11 = v1[e4 * 4 + 1] - m4.y;
            float d02 = v0[e4 * 4 + 2] - m4.z, d12 = v1[e4 * 4 + 2] - m4.z;
            float d03 = v0[e4 * 4 + 3] - m4.w, d13 = v1[e4 * 4 + 3] - m4.w;
            float t0 = fmaf(r1_0 * d00, d00, r1_1 * d10 * d10);
            float t1 = fmaf(r1_0 * d01, d01, r1_1 * d11 * d11);
            float t2 = fmaf(r1_0 * d02, d02, r1_1 * d12 * d12);
            float t3 = fmaf(r1_0 * d03, d03, r1_1 * d13 * d13);
            t0 += __shfl_xor(t0, 16, 64); t0 += __shfl_xor(t0, 32, 64);
            t1 += __shfl_xor(t1, 16, 64); t1 += __shfl_xor(t1, 32, 64);
            t2 += __shfl_xor(t2, 16, 64); t2 += __shfl_xor(t2, 32, 64);
            t3 += __shfl_xor(t3, 16, 64); t3 += __shfl_xor(t3, 32, 64);
            if (lane < NOUTV)
                *(float4*)&red[wid][lane][e4 * 4] = make_float4(t0, t1, t2, t3);
        }
        __syncthreads();                                  // (4)
        float sg0 = 0.0f, sg1 = 0.0f;
        #pragma unroll
        for (int w2 = 0; w2 < 8; ++w2) {
            sg0 += red[w2][o_f0][e_f];
            sg1 += red[w2][o_f1][e_f];
        }
        const float ss0 = sg0 + EPSF;
        const float ss1 = sg1 + EPSF;
        const float hl0 = 0.5f * logf(ss0);
        const float hl1 = 0.5f * logf(ss1);
        inv2s_sh[o_f0][e_f] = 0.5f / ss0;
        inv2s_sh[o_f1][e_f] = 0.5f / ss1;
        float arsum_f0 = 0.0f, arsum_f1 = 0.0f;
        #pragma unroll
        for (int w2 = 0; w2 < 8; ++w2) {
            arsum_f0 += red_s[w2][o_f0];
            arsum_f1 += red_s[w2][o_f1];
        }
        float sh0 = hl0, sh1 = hl1;
        sh0 += __shfl_xor(sh0, 1, 64);   sh1 += __shfl_xor(sh1, 1, 64);
        sh0 += __shfl_xor(sh0, 2, 64);   sh1 += __shfl_xor(sh1, 2, 64);
        sh0 += __shfl_xor(sh0, 4, 64);   sh1 += __shfl_xor(sh1, 4, 64);
        sh0 += __shfl_xor(sh0, 8, 64);   sh1 += __shfl_xor(sh1, 8, 64);
        sh0 += __shfl_xor(sh0, 16, 64);  sh1 += __shfl_xor(sh1, 16, 64);
        sh0 += __shfl_xor(sh0, 32, 64);  sh1 += __shfl_xor(sh1, 32, 64);
        if (lane == 0) {
            sumhl_sh[o_f0] = sh0;
            sumhl_sh[o_f1] = sh1;
            const float cost0 = 64.0f * beta_u[o_f0] + arsum_f0 * sh0;
            const float cost1 = 64.0f * beta_u[o_f1] + arsum_f1 * sh1;
            logact_sh[o_f0] = logf(1.0f / (1.0f + expf(-(LBDF * (beta_a[o_f0] - cost0)))));
            logact_sh[o_f1] = logf(1.0f / (1.0f + expf(-(LBDF * (beta_a[o_f1] - cost1)))));
        }
        __syncthreads();                                  // (5)

        // ---- e_step (per pair; mu/inv2s rows shared since o is shared) ----
        float acc0 = 0.0f, acc1 = 0.0f;
        #pragma unroll
        for (int e4 = 0; e4 < EE / 4; ++e4) {
            const float4 m4 = *(const float4*)&mu_sh[o][e4 * 4];
            const float4 i4 = *(const float4*)&inv2s_sh[o][e4 * 4];
            float d00 = v0[e4 * 4 + 0] - m4.x, d10 = v1[e4 * 4 + 0] - m4.x;
            float d01 = v0[e4 * 4 + 1] - m4.y, d11 = v1[e4 * 4 + 1] - m4.y;
            float d02 = v0[e4 * 4 + 2] - m4.z, d12 = v1[e4 * 4 + 2] - m4.z;
            float d03 = v0[e4 * 4 + 3] - m4.w, d13 = v1[e4 * 4 + 3] - m4.w;
            acc0 = fmaf(d00 * d00, i4.x, acc0);  acc1 = fmaf(d10 * d10, i4.x, acc1);
            acc0 = fmaf(d01 * d01, i4.y, acc0);  acc1 = fmaf(d11 * d11, i4.y, acc1);
            acc0 = fmaf(d02 * d02, i4.z, acc0);  acc1 = fmaf(d12 * d12, i4.z, acc1);
            acc0 = fmaf(d03 * d03, i4.w, acc0);  acc1 = fmaf(d13 * d13, i4.w, acc1);
        }
        float la0 = -acc0 - sumhl_sh[o] - SUM_LN2PI + logact_sh[o];
        float la1 = -acc1 - sumhl_sh[o] - SUM_LN2PI + logact_sh[o];
        if (msk0) la0 = -10000.0f;
        if (msk1) la1 = -10000.0f;
        float mx0 = la0, mx1 = la1;
        mx0 = fmaxf(mx0, __shfl_xor(mx0, 1, 64));  mx1 = fmaxf(mx1, __shfl_xor(mx1, 1, 64));
        mx0 = fmaxf(mx0, __shfl_xor(mx0, 2, 64));  mx1 = fmaxf(mx1, __shfl_xor(mx1, 2, 64));
        mx0 = fmaxf(mx0, __shfl_xor(mx0, 4, 64));  mx1 = fmaxf(mx1, __shfl_xor(mx1, 4, 64));
        mx0 = fmaxf(mx0, __shfl_xor(mx0, 8, 64));  mx1 = fmaxf(mx1, __shfl_xor(mx1, 8, 64));
        const float ex0 = expf(la0 - mx0);
        const float ex1 = expf(la1 - mx1);
        float se0 = ex0, se1 = ex1;
        se0 += __shfl_xor(se0, 1, 64);  se1 += __shfl_xor(se1, 1, 64);
        se0 += __shfl_xor(se0, 2, 64);  se1 += __shfl_xor(se1, 2, 64);
        se0 += __shfl_xor(se0, 4, 64);  se1 += __shfl_xor(se1, 4, 64);
        se0 += __shfl_xor(se0, 8, 64);  se1 += __shfl_xor(se1, 8, 64);
        r_loc0 = ex0 / se0;
        r_loc1 = ex1 / se1;
    }

    out_r[bl * 1024 + n0 * NOUTV + o] = r_loc0;
    out_r[bl * 1024 + n1 * NOUTV + o] = r_loc1;
}

// ---------------------------------------------------------------------------
extern "C" void kernel_launch(void* const* d_in, const int* in_sizes, int n_in,
                              void* d_out, int out_size, void* d_ws, size_t ws_size,
                              hipStream_t stream) {
    const float* inu            = (const float*)d_in[0];
    const unsigned char* mask   = (const unsigned char*)d_in[1];
    const float* ctx            = (const float*)d_in[2];
    const float* rw             = (const float*)d_in[3];
    const float* Wu             = (const float*)d_in[4];
    const float* bu             = (const float*)d_in[5];
    const float* Wc             = (const float*)d_in[6];
    const float* bc             = (const float*)d_in[7];
    const float* Wv             = (const float*)d_in[8];
    const float* bv             = (const float*)d_in[9];
    const float* Wa             = (const float*)d_in[10];
    const float* ba             = (const float*)d_in[11];
    const float* beta_u         = (const float*)d_in[12];
    const float* beta_a         = (const float*)d_in[13];

    float* u_ws = (float*)d_ws;                       // B*NIN*NOUT*E = 524288 f32
    float* c_ws = u_ws + (size_t)BB * NINV * NOUTV * EE;
    float* a_ws = c_ws + (size_t)BB * LL * EE;        // B*NIN = 512 f32

    float* out_mu = (float*)d_out;
    float* out_r  = out_mu + (size_t)BB * LL * NOUTV * EE;

    prep_kernel<<<BB * LL + BB, 64, 0, stream>>>(ctx, Wc, bc, inu, Wa, ba, c_ws, a_ws);
    priors_u_kernel<<<NINV * NOUTV, 256, 0, stream>>>(inu, rw, Wu, bu, u_ws);
    votes_em_kernel<<<BB * LL, 512, 0, stream>>>(u_ws, c_ws, a_ws, mask, Wv, bv,
                                                 beta_u, beta_a, out_mu, out_r);
}

// Round 6
// 81.229 us; speedup vs baseline: 1.1327x; 1.1327x over previous
//
#include <hip/hip_runtime.h>
#include <hip/hip_bf16.h>

// Problem dims (fixed)
#define BB   8
#define LL   32
#define NINV 64
#define NOUTV 16
#define DINV 128
#define EE   64
#define DCV  512

#define EPSF 1e-8f
#define LBDF 1e-3f
// 32 * ln(2*pi)
#define SUM_LN2PI 58.8120661250990508f

typedef float f32x2 __attribute__((ext_vector_type(2)));

static __device__ __forceinline__ f32x2 pkfma(f32x2 a, f32x2 b, f32x2 c) {
    return __builtin_elementwise_fma(a, b, c);   // -> v_pk_fma_f32
}

// ---------------------------------------------------------------------------
// Kernel 1: c[b,l,e] = ctx[b,l,:]@Wc + bc   (blocks 0..255)
//           actn[b,n] = sigmoid(inu[b,n,:]@Wa + ba)  (blocks 256..263)
// ---------------------------------------------------------------------------
__global__ __launch_bounds__(64) void prep_kernel(
    const float* __restrict__ ctx, const float* __restrict__ Wc, const float* __restrict__ bc,
    const float* __restrict__ inu, const float* __restrict__ Wa, const float* __restrict__ ba,
    float* __restrict__ c_out, float* __restrict__ actn_out)
{
    const int blk = blockIdx.x;
    const int t = threadIdx.x;
    __shared__ float row[DCV];
    if (blk < BB * LL) {
        const float* cr = ctx + (size_t)blk * DCV;
        #pragma unroll
        for (int i = 0; i < DCV / 64; ++i) row[t + 64 * i] = cr[t + 64 * i];
        __syncthreads();
        float acc = bc[t];
        for (int d = 0; d < DCV; ++d) acc = fmaf(row[d], Wc[d * EE + t], acc);
        c_out[blk * EE + t] = acc;
    } else {
        const int b = blk - BB * LL;
        const float* ir = inu + ((size_t)b * NINV + t) * DINV;
        float acc = ba[0];
        for (int d = 0; d < DINV; ++d) acc = fmaf(ir[d], Wa[d], acc);
        actn_out[b * NINV + t] = 1.0f / (1.0f + expf(-acc));
    }
}

// ---------------------------------------------------------------------------
// Kernel 2: block (n,o):
//   priors[b,e] = sum_d inu[b,n,d] * rw[n,o,d,e]   (8x128 @ 128x64)
//   u[b,n,o,e]  = priors[b,:] @ Wu + bu
// ---------------------------------------------------------------------------
__global__ __launch_bounds__(256) void priors_u_kernel(
    const float* __restrict__ inu, const float* __restrict__ rw,
    const float* __restrict__ Wu, const float* __restrict__ bu,
    float* __restrict__ u_out)
{
    const int no = blockIdx.x;      // n*16+o
    const int n  = no >> 4;
    const int oo = no & 15;
    const int tid = threadIdx.x;

    __shared__ float inu_sh[BB * DINV];   // 4 KB
    __shared__ float pri_sh[BB * EE];     // 2 KB

    {   // stage inu[:, n, :]
        const int b = tid >> 5;
        const int i = (tid & 31) * 4;
        const float4 s = *(const float4*)(inu + ((size_t)b * NINV + n) * DINV + i);
        *(float4*)(inu_sh + b * DINV + i) = s;
    }
    __syncthreads();

    const int bg = tid >> 6;   // 0..3 -> handles b = 2bg, 2bg+1
    const int e  = tid & 63;
    const float* rwp = rw + (size_t)no * DINV * EE + e;
    const float* r0 = inu_sh + (bg * 2) * DINV;
    const float* r1 = inu_sh + (bg * 2 + 1) * DINV;
    float a0 = 0.0f, a1 = 0.0f;
    for (int d = 0; d < DINV; ++d) {
        const float w = rwp[d * EE];
        a0 = fmaf(r0[d], w, a0);
        a1 = fmaf(r1[d], w, a1);
    }
    pri_sh[(bg * 2) * EE + e] = a0;
    pri_sh[(bg * 2 + 1) * EE + e] = a1;
    __syncthreads();

    float b0 = bu[e], b1 = b0;
    const float* p0 = pri_sh + (bg * 2) * EE;
    const float* p1 = pri_sh + (bg * 2 + 1) * EE;
    for (int e1 = 0; e1 < EE; ++e1) {
        const float w = Wu[e1 * EE + e];
        b0 = fmaf(p0[e1], w, b0);
        b1 = fmaf(p1[e1], w, b1);
    }
    u_out[(((size_t)(bg * 2) * NINV + n) * NOUTV + oo) * EE + e] = b0;
    u_out[(((size_t)(bg * 2 + 1) * NINV + n) * NOUTV + oo) * EE + e] = b1;
}

// ---------------------------------------------------------------------------
// Kernel 3: one 512-thread workgroup per (b,l). Thread owns TWO (n,o) pairs
// sharing o (n0, n1=n0+32); votes held as f32x2[32] per pair.
// Round-6: (a) v_pk_fma_f32 inner GEMM (halves issue count), (b) fused
// single-pass EM reduction: S1=sum ar*v, S2=sum ar*v^2, A=sum ar;
// mu=S1/D, sigma=S2/D-mu^2 (D=A+eps). Cancellation error ~3e-14 abs,
// negligible vs s=sigma+1e-8. 2 barriers/iter instead of 5.
// Wv reverted to GLOBAL (R5 showed LDS broadcast costs ~5us of ds issue).
// ---------------------------------------------------------------------------
__global__ __launch_bounds__(512, 2) void votes_em_kernel(
    const float* __restrict__ u_all, const float* __restrict__ c_all,
    const float* __restrict__ actn_all, const unsigned char* __restrict__ mask_all,
    const float* __restrict__ Wv, const float* __restrict__ bv,
    const float* __restrict__ beta_u, const float* __restrict__ beta_a,
    float* __restrict__ out_mu, float* __restrict__ out_r)
{
    const int bl = blockIdx.x;           // 0..255
    const int b = bl >> 5;
    const int tid = threadIdx.x;
    const int lane = tid & 63;
    const int wid = tid >> 6;            // wave id 0..7
    const int o = lane & 15;
    const int n0 = (wid << 2) | (lane >> 4);   // 0..31
    const int n1 = n0 + 32;                    // 32..63
    const int e_f = lane;                      // finalize role: e = lane,
    const int o_f0 = wid;                      // o in {wid, wid+8}
    const int o_f1 = wid + 8;

    __shared__ float c_sh[EE];
    __shared__ float actn_sh[NINV];
    __shared__ float red[8][NOUTV][2 * EE + 4];  // 67.6 KB: [.. , e]=S1, [..,64+e]=S2
    __shared__ float red_s[8][NOUTV];
    __shared__ float mu_sh[NOUTV][EE + 4];
    __shared__ float inv2s_sh[NOUTV][EE + 4];
    __shared__ float sumhl_sh[NOUTV];
    __shared__ float logact_sh[NOUTV];

    if (tid < EE) c_sh[tid] = c_all[bl * EE + tid];
    else if (tid >= 64 && tid < 128) actn_sh[tid - 64] = actn_all[b * NINV + (tid - 64)];
    __syncthreads();

    // ---- votes[n,o,e] = sum_e1 tanh(u[e1]+c[e1]) * Wv[e1][e] + bv[e] ----
    f32x2 v0p[32], v1p[32];
    #pragma unroll
    for (int k = 0; k < 32; ++k) {
        const f32x2 bb = *(const f32x2*)(bv + 2 * k);   // uniform -> s_load
        v0p[k] = bb;
        v1p[k] = bb;
    }
    const float4* u4_0 = (const float4*)(u_all + (((size_t)b * NINV + n0) * NOUTV + o) * EE);
    const float4* u4_1 = (const float4*)(u_all + (((size_t)b * NINV + n1) * NOUTV + o) * EE);
    float4 uu0 = u4_0[0];
    float4 uu1 = u4_1[0];
    for (int cc = 0; cc < 16; ++cc) {
        const float4 nx0 = (cc < 15) ? u4_0[cc + 1] : uu0;
        const float4 nx1 = (cc < 15) ? u4_1[cc + 1] : uu1;
        #pragma unroll
        for (int j = 0; j < 4; ++j) {
            const int e1 = cc * 4 + j;
            const float ce = c_sh[e1];
            const float x0 = ((const float*)&uu0)[j] + ce;
            const float x1 = ((const float*)&uu1)[j] + ce;
            // tanh(x) = 1 - 2/(e^{2x}+1)
            const float t0 = 1.0f - 2.0f / (__expf(2.0f * x0) + 1.0f);
            const float t1 = 1.0f - 2.0f / (__expf(2.0f * x1) + 1.0f);
            const f32x2 t02 = {t0, t0};
            const f32x2 t12 = {t1, t1};
            const f32x2* w2 = (const f32x2*)(Wv + e1 * EE);   // uniform -> s_load
            #pragma unroll
            for (int k = 0; k < 32; ++k) {
                const f32x2 w = w2[k];
                v0p[k] = pkfma(t02, w, v0p[k]);
                v1p[k] = pkfma(t12, w, v1p[k]);
            }
        }
        uu0 = nx0;
        uu1 = nx1;
    }

    const unsigned char msk0 = mask_all[b * NINV + n0];
    const unsigned char msk1 = mask_all[b * NINV + n1];
    float r_loc0 = 1.0f / 16.0f;
    float r_loc1 = 1.0f / 16.0f;

    for (int it = 0; it < 3; ++it) {
        // ---- ar (normalized over o) + arsum wave-partial ----
        float ar0 = actn_sh[n0] * r_loc0;
        float ar1 = actn_sh[n1] * r_loc1;
        float s0 = ar0, s1 = ar1;
        s0 += __shfl_xor(s0, 1, 64);  s1 += __shfl_xor(s1, 1, 64);
        s0 += __shfl_xor(s0, 2, 64);  s1 += __shfl_xor(s1, 2, 64);
        s0 += __shfl_xor(s0, 4, 64);  s1 += __shfl_xor(s1, 4, 64);
        s0 += __shfl_xor(s0, 8, 64);  s1 += __shfl_xor(s1, 8, 64);
        ar0 = ar0 / (s0 + EPSF);
        ar1 = ar1 / (s1 + EPSF);
        float p = ar0 + ar1;
        p += __shfl_xor(p, 16, 64);
        p += __shfl_xor(p, 32, 64);
        if (lane < NOUTV) red_s[wid][lane] = p;

        const f32x2 ar02 = {ar0, ar0};
        const f32x2 ar12 = {ar1, ar1};

        if (it < 2) {
            // ---- single reduction pass: S1 = sum ar*v, S2 = sum ar*v^2 ----
            #pragma unroll
            for (int k = 0; k < 32; ++k) {
                const f32x2 p0 = ar02 * v0p[k];
                const f32x2 p1 = ar12 * v1p[k];
                f32x2 m2 = p0 + p1;
                f32x2 q2 = pkfma(p0, v0p[k], p1 * v1p[k]);
                float m0 = m2[0], m1 = m2[1], q0 = q2[0], q1 = q2[1];
                m0 += __shfl_xor(m0, 16, 64); m0 += __shfl_xor(m0, 32, 64);
                m1 += __shfl_xor(m1, 16, 64); m1 += __shfl_xor(m1, 32, 64);
                q0 += __shfl_xor(q0, 16, 64); q0 += __shfl_xor(q0, 32, 64);
                q1 += __shfl_xor(q1, 16, 64); q1 += __shfl_xor(q1, 32, 64);
                if (lane < NOUTV) {
                    const f32x2 mw = {m0, m1};
                    const f32x2 qw = {q0, q1};
                    *(f32x2*)&red[wid][lane][2 * k] = mw;
                    *(f32x2*)&red[wid][lane][EE + 2 * k] = qw;
                }
            }
            __syncthreads();                              // (A)

            // ---- finalize: mu, sigma, hl, inv2s, cost/logact ----
            float S10 = 0.0f, S20 = 0.0f, S11 = 0.0f, S21 = 0.0f;
            float A0 = 0.0f, A1 = 0.0f;
            #pragma unroll
            for (int w2i = 0; w2i < 8; ++w2i) {
                S10 += red[w2i][o_f0][e_f];
                S20 += red[w2i][o_f0][EE + e_f];
                S11 += red[w2i][o_f1][e_f];
                S21 += red[w2i][o_f1][EE + e_f];
                A0  += red_s[w2i][o_f0];
                A1  += red_s[w2i][o_f1];
            }
            const float iD0 = 1.0f / (A0 + EPSF);
            const float iD1 = 1.0f / (A1 + EPSF);
            const float mu0 = S10 * iD0;
            const float mu1 = S11 * iD1;
            const float sv0 = fmaf(-mu0, mu0, S20 * iD0) + EPSF;
            const float sv1 = fmaf(-mu1, mu1, S21 * iD1) + EPSF;
            const float hl0 = 0.5f * logf(sv0);
            const float hl1 = 0.5f * logf(sv1);
            mu_sh[o_f0][e_f] = mu0;
            mu_sh[o_f1][e_f] = mu1;
            inv2s_sh[o_f0][e_f] = 0.5f / sv0;
            inv2s_sh[o_f1][e_f] = 0.5f / sv1;
            float sh0 = hl0, sh1 = hl1;
            sh0 += __shfl_xor(sh0, 1, 64);   sh1 += __shfl_xor(sh1, 1, 64);
            sh0 += __shfl_xor(sh0, 2, 64);   sh1 += __shfl_xor(sh1, 2, 64);
            sh0 += __shfl_xor(sh0, 4, 64);   sh1 += __shfl_xor(sh1, 4, 64);
            sh0 += __shfl_xor(sh0, 8, 64);   sh1 += __shfl_xor(sh1, 8, 64);
            sh0 += __shfl_xor(sh0, 16, 64);  sh1 += __shfl_xor(sh1, 16, 64);
            sh0 += __shfl_xor(sh0, 32, 64);  sh1 += __shfl_xor(sh1, 32, 64);
            if (lane == 0) {
                sumhl_sh[o_f0] = sh0;
                sumhl_sh[o_f1] = sh1;
                const float cost0 = 64.0f * beta_u[o_f0] + A0 * sh0;
                const float cost1 = 64.0f * beta_u[o_f1] + A1 * sh1;
                logact_sh[o_f0] = logf(1.0f / (1.0f + expf(-(LBDF * (beta_a[o_f0] - cost0)))));
                logact_sh[o_f1] = logf(1.0f / (1.0f + expf(-(LBDF * (beta_a[o_f1] - cost1)))));
            }
            __syncthreads();                              // (B)

            // ---- e_step ----
            f32x2 a0v = {0.0f, 0.0f};
            f32x2 a1v = {0.0f, 0.0f};
            #pragma unroll
            for (int k = 0; k < 32; ++k) {
                const f32x2 m2 = *(const f32x2*)&mu_sh[o][2 * k];
                const f32x2 i2 = *(const f32x2*)&inv2s_sh[o][2 * k];
                const f32x2 d0 = v0p[k] - m2;
                const f32x2 d1 = v1p[k] - m2;
                a0v = pkfma(d0 * d0, i2, a0v);
                a1v = pkfma(d1 * d1, i2, a1v);
            }
            const float acc0 = a0v[0] + a0v[1];
            const float acc1 = a1v[0] + a1v[1];
            float la0 = -acc0 - sumhl_sh[o] - SUM_LN2PI + logact_sh[o];
            float la1 = -acc1 - sumhl_sh[o] - SUM_LN2PI + logact_sh[o];
            if (msk0) la0 = -10000.0f;
            if (msk1) la1 = -10000.0f;
            float mx0 = la0, mx1 = la1;
            mx0 = fmaxf(mx0, __shfl_xor(mx0, 1, 64));  mx1 = fmaxf(mx1, __shfl_xor(mx1, 1, 64));
            mx0 = fmaxf(mx0, __shfl_xor(mx0, 2, 64));  mx1 = fmaxf(mx1, __shfl_xor(mx1, 2, 64));
            mx0 = fmaxf(mx0, __shfl_xor(mx0, 4, 64));  mx1 = fmaxf(mx1, __shfl_xor(mx1, 4, 64));
            mx0 = fmaxf(mx0, __shfl_xor(mx0, 8, 64));  mx1 = fmaxf(mx1, __shfl_xor(mx1, 8, 64));
            const float ex0 = __expf(la0 - mx0);
            const float ex1 = __expf(la1 - mx1);
            float se0 = ex0, se1 = ex1;
            se0 += __shfl_xor(se0, 1, 64);  se1 += __shfl_xor(se1, 1, 64);
            se0 += __shfl_xor(se0, 2, 64);  se1 += __shfl_xor(se1, 2, 64);
            se0 += __shfl_xor(se0, 4, 64);  se1 += __shfl_xor(se1, 4, 64);
            se0 += __shfl_xor(se0, 8, 64);  se1 += __shfl_xor(se1, 8, 64);
            r_loc0 = ex0 / se0;
            r_loc1 = ex1 / se1;
        } else {
            // ---- final m_step: mu only ----
            #pragma unroll
            for (int k = 0; k < 32; ++k) {
                f32x2 m2 = pkfma(ar02, v0p[k], ar12 * v1p[k]);
                float m0 = m2[0], m1 = m2[1];
                m0 += __shfl_xor(m0, 16, 64); m0 += __shfl_xor(m0, 32, 64);
                m1 += __shfl_xor(m1, 16, 64); m1 += __shfl_xor(m1, 32, 64);
                if (lane < NOUTV) {
                    const f32x2 mw = {m0, m1};
                    *(f32x2*)&red[wid][lane][2 * k] = mw;
                }
            }
            __syncthreads();                              // (A)
            float S10 = 0.0f, S11 = 0.0f, A0 = 0.0f, A1 = 0.0f;
            #pragma unroll
            for (int w2i = 0; w2i < 8; ++w2i) {
                S10 += red[w2i][o_f0][e_f];
                S11 += red[w2i][o_f1][e_f];
                A0  += red_s[w2i][o_f0];
                A1  += red_s[w2i][o_f1];
            }
            out_mu[bl * 1024 + o_f0 * EE + e_f] = S10 / (A0 + EPSF);
            out_mu[bl * 1024 + o_f1 * EE + e_f] = S11 / (A1 + EPSF);
        }
    }

    out_r[bl * 1024 + n0 * NOUTV + o] = r_loc0;
    out_r[bl * 1024 + n1 * NOUTV + o] = r_loc1;
}

// ---------------------------------------------------------------------------
extern "C" void kernel_launch(void* const* d_in, const int* in_sizes, int n_in,
                              void* d_out, int out_size, void* d_ws, size_t ws_size,
                              hipStream_t stream) {
    const float* inu            = (const float*)d_in[0];
    const unsigned char* mask   = (const unsigned char*)d_in[1];
    const float* ctx            = (const float*)d_in[2];
    const float* rw             = (const float*)d_in[3];
    const float* Wu             = (const float*)d_in[4];
    const float* bu             = (const float*)d_in[5];
    const float* Wc             = (const float*)d_in[6];
    const float* bc             = (const float*)d_in[7];
    const float* Wv             = (const float*)d_in[8];
    const float* bv             = (const float*)d_in[9];
    const float* Wa             = (const float*)d_in[10];
    const float* ba             = (const float*)d_in[11];
    const float* beta_u         = (const float*)d_in[12];
    const float* beta_a         = (const float*)d_in[13];

    float* u_ws = (float*)d_ws;                       // B*NIN*NOUT*E = 524288 f32
    float* c_ws = u_ws + (size_t)BB * NINV * NOUTV * EE;
    float* a_ws = c_ws + (size_t)BB * LL * EE;        // B*NIN = 512 f32

    float* out_mu = (float*)d_out;
    float* out_r  = out_mu + (size_t)BB * LL * NOUTV * EE;

    prep_kernel<<<BB * LL + BB, 64, 0, stream>>>(ctx, Wc, bc, inu, Wa, ba, c_ws, a_ws);
    priors_u_kernel<<<NINV * NOUTV, 256, 0, stream>>>(inu, rw, Wu, bu, u_ws);
    votes_em_kernel<<<BB * LL, 512, 0, stream>>>(u_ws, c_ws, a_ws, mask, Wv, bv,
                                                 beta_u, beta_a, out_mu, out_r);
}